// Round 13
// baseline (1113.692 us; speedup 1.0000x reference)
//
#include <hip/hip_runtime.h>
#include <hip/hip_bf16.h>
#include <hip/hip_cooperative_groups.h>

namespace cg = cooperative_groups;

// ---- types ----
typedef __attribute__((ext_vector_type(8))) short short8_t;   // 8 x bf16 (4 VGPR)
typedef __attribute__((ext_vector_type(4))) float f32x4;      // MFMA acc / native float4

__device__ __forceinline__ short f2bf(float f) {
    union { float f; unsigned u; } v; v.f = f;
    unsigned r = (v.u + 0x7FFFu + ((v.u >> 16) & 1u)) >> 16;  // RNE
    return (short)r;
}

// non-temporal float4 helpers: u/out bypass cache hierarchy so the L3 keeps v.
__device__ __forceinline__ f32x4 ntload4(const float* p) {
    return __builtin_nontemporal_load(reinterpret_cast<const f32x4*>(p));
}
__device__ __forceinline__ void ntstore4(float* p, f32x4 v) {
    __builtin_nontemporal_store(v, reinterpret_cast<f32x4*>(p));
}

// Geometry: x[8][256][256][256] fp32. u = c in [0,128), v = c in [128,256).
// Per batch: 32768 rows (2048 16-row tiles). Block slice: 8 tiles = 32768 floats.
#define N_PER_BATCH 8388608.0f
#define LDR 264                  // padded LDS row (bf16): A-reads 2-way banks (free)

// ================== persistent cooperative kernel =========================
// Phase A0: stats of batch 0 -> partials[0][b]; grid.sync.
// Phase B_g (g=0..7): finalize stats(g) from partials (redundant per block),
// GEMM+gate batch g (v L3-hot from previous phase; u/out non-temporal),
// interleaved streaming read of v_{g+1} accumulating stats -> partials[g+1][b];
// grid.sync. v touches HBM exactly once.
__global__ __launch_bounds__(1024, 4) void mega(const float* __restrict__ x,
                                                const float* __restrict__ W,
                                                const float* __restrict__ bias,
                                                float2* __restrict__ partials,
                                                float* __restrict__ out) {
    cg::grid_group grid = cg::this_grid();
    __shared__ short vt[2][16 * LDR];   // 16896 B
    __shared__ float2 red2[16];
    __shared__ float2 bstL;
    const int tid  = threadIdx.x;
    const int wid  = tid >> 6;
    const int lane = tid & 63;
    const int l15  = lane & 15;
    const int l4   = lane >> 4;
    const int q    = l15 & 3;
    const int qg   = l15 >> 2;
    const int b    = blockIdx.x;

    // ---- B fragments: W[col][k], col = wid*16 + l15, k = kb*32 + l4*8 + j ----
    short8_t bfrag[8];
    {
        const float* wbase = W + (size_t)(wid * 16 + l15) * 256 + (l4 << 3);
        #pragma unroll
        for (int kb = 0; kb < 8; ++kb) {
            float4 p0 = *reinterpret_cast<const float4*>(wbase + kb * 32);
            float4 p1 = *reinterpret_cast<const float4*>(wbase + kb * 32 + 4);
            short8_t s;
            s[0] = f2bf(p0.x); s[1] = f2bf(p0.y); s[2] = f2bf(p0.z); s[3] = f2bf(p0.w);
            s[4] = f2bf(p1.x); s[5] = f2bf(p1.y); s[6] = f2bf(p1.z); s[7] = f2bf(p1.w);
            bfrag[kb] = s;
        }
    }
    float4 bq = *reinterpret_cast<const float4*>(bias + wid * 16 + (qg << 2));
    bq.x += 1.f; bq.y += 1.f; bq.z += 1.f; bq.w += 1.f;

    // staging / epilogue lane roles (as proven in rounds 5-12)
    const int   srow = tid >> 6;
    const int   scol = (tid & 63) << 2;
    const size_t goff = (size_t)srow * 256 + scol;
    const int   ldsw = srow * LDR + scol;
    const size_t eoff = (size_t)(l4 * 4 + q) * 256 + wid * 16 + (qg << 2);
    const int   aoff = l15 * LDR + (l4 << 3);

    // ---- Phase A0: stats of batch 0, block slice = b*32768 floats ----
    {
        const float* sb = x + (1u << 23) + ((size_t)b << 15) + (tid << 2);
        float aS = 0.f, aQ = 0.f;
        #pragma unroll
        for (int i = 0; i < 8; ++i) {
            f32x4 v = *reinterpret_cast<const f32x4*>(sb + (i << 12));
            aS += v[0] + v[1] + v[2] + v[3];
            aQ += v[0]*v[0] + v[1]*v[1] + v[2]*v[2] + v[3]*v[3];
        }
        float r1 = aS, r2 = aQ;
        #pragma unroll
        for (int off = 32; off; off >>= 1) {
            r1 += __shfl_xor(r1, off);
            r2 += __shfl_xor(r2, off);
        }
        if (lane == 0) red2[wid] = make_float2(r1, r2);
        __syncthreads();
        if (wid == 0 && lane < 16) {
            float2 pr = red2[lane];
            float s1 = pr.x, s2 = pr.y;
            s1 += __shfl_xor(s1, 8);  s2 += __shfl_xor(s2, 8);
            s1 += __shfl_xor(s1, 4);  s2 += __shfl_xor(s2, 4);
            s1 += __shfl_xor(s1, 2);  s2 += __shfl_xor(s2, 2);
            s1 += __shfl_xor(s1, 1);  s2 += __shfl_xor(s2, 1);
            if (lane == 0) partials[b] = make_float2(s1, s2);
        }
    }
    __threadfence();
    grid.sync();

    for (int g = 0; g < 8; ++g) {
        // ---- finalize stats(g) redundantly from partials[g][0..255] ----
        if (wid == 0) {
            const float2* pg = partials + ((size_t)g << 8) + (lane << 2);
            float2 p0 = pg[0], p1 = pg[1], p2 = pg[2], p3 = pg[3];
            float s1 = p0.x + p1.x + p2.x + p3.x;
            float s2 = p0.y + p1.y + p2.y + p3.y;
            #pragma unroll
            for (int off = 32; off; off >>= 1) {
                s1 += __shfl_xor(s1, off);
                s2 += __shfl_xor(s2, off);
            }
            if (lane == 0) {
                float mean = s1 / N_PER_BATCH;
                float var  = s2 / N_PER_BATCH - mean * mean;
                bstL = make_float2(mean, rsqrtf(var + 1e-5f));
            }
        }
        __syncthreads();
        const float mean = bstL.x, rstd = bstL.y;

        // phase pointers: block slice = 8 tiles of batch g
        const float* vbase = x + ((size_t)g << 24) + (1u << 23) + ((size_t)b << 15);
        const float* ubase = x + ((size_t)g << 24) + ((size_t)b << 15);
        float*       obase = out + (((size_t)(g * 2048 + b * 8)) << 12);
        const float* sbase = x + ((size_t)(g + 1) << 24) + (1u << 23) + ((size_t)b << 15);
        const bool   doStats = (g < 7);

        // ---- prologue: stage tile 0; prefetch v(1), u(0), u(1), s(0) ----
        {
            f32x4 v0 = *reinterpret_cast<const f32x4*>(vbase + goff);
            short4 s;
            s.x = f2bf((v0[0] - mean) * rstd); s.y = f2bf((v0[1] - mean) * rstd);
            s.z = f2bf((v0[2] - mean) * rstd); s.w = f2bf((v0[3] - mean) * rstd);
            *reinterpret_cast<short4*>(&vt[0][ldsw]) = s;
        }
        f32x4 vA = *reinterpret_cast<const f32x4*>(vbase + (1u << 12) + goff);
        f32x4 uA = ntload4(ubase + eoff);
        f32x4 uB = ntload4(ubase + (1u << 12) + eoff);
        f32x4 sA = {0.f, 0.f, 0.f, 0.f};
        if (doStats) sA = *reinterpret_cast<const f32x4*>(sbase + (tid << 2));
        float aS = 0.f, aQ = 0.f;
        asm volatile("s_waitcnt lgkmcnt(0)" ::: "memory");
        __builtin_amdgcn_s_barrier();

        for (int i = 0; i < 8; ++i) {
            const int cur = i & 1;
            const int ip1 = (i + 1 < 8) ? i + 1 : 7;
            const int ip2 = (i + 2 < 8) ? i + 2 : 7;

            // deep prefetches first (stay in flight across the barrier)
            f32x4 vB = *reinterpret_cast<const f32x4*>(vbase + ((size_t)ip2 << 12) + goff);
            f32x4 uC = ntload4(ubase + ((size_t)ip2 << 12) + eoff);
            f32x4 sB = sA;
            if (doStats) sB = *reinterpret_cast<const f32x4*>(sbase + ((size_t)ip1 << 12) + (tid << 2));

            // ---- MFMA over K=256 ----
            f32x4 acc = {0.f, 0.f, 0.f, 0.f};
            #pragma unroll
            for (int kb = 0; kb < 8; ++kb) {
                short8_t a = *reinterpret_cast<const short8_t*>(&vt[cur][aoff + kb * 32]);
                acc = __builtin_amdgcn_mfma_f32_16x16x32_bf16(a, bfrag[kb], acc, 0, 0, 0);
            }

            // ---- 4x4 transpose within lane quads ----
            float a0 = acc[0], a1 = acc[1], a2 = acc[2], a3 = acc[3];
            float e0 = __shfl_xor(a1, 1), e1 = __shfl_xor(a0, 1);
            float e2 = __shfl_xor(a3, 1), e3 = __shfl_xor(a2, 1);
            const bool qb0 = (q & 1);
            float w0 = qb0 ? e0 : a0;
            float w1 = qb0 ? a1 : e1;
            float w2 = qb0 ? e2 : a2;
            float w3 = qb0 ? a3 : e3;
            float t0 = __shfl_xor(w2, 2), t1 = __shfl_xor(w3, 2);
            float t2 = __shfl_xor(w0, 2), t3 = __shfl_xor(w1, 2);
            const bool qb1 = (q & 2);
            float x0 = qb1 ? t0 : w0;
            float x1 = qb1 ? t1 : w1;
            float x2 = qb1 ? w2 : t2;
            float x3 = qb1 ? w3 : t3;

            // ---- epilogue: out = u * (y + b + 1), non-temporal ----
            f32x4 o;
            o[0] = uA[0] * (x0 + bq.x);
            o[1] = uA[1] * (x1 + bq.y);
            o[2] = uA[2] * (x2 + bq.z);
            o[3] = uA[3] * (x3 + bq.w);
            ntstore4(obase + ((size_t)i << 12) + eoff, o);

            // ---- accumulate stats of v_{g+1} slab i ----
            if (doStats) {
                aS += sA[0] + sA[1] + sA[2] + sA[3];
                aQ += sA[0]*sA[0] + sA[1]*sA[1] + sA[2]*sA[2] + sA[3]*sA[3];
            }

            // ---- stage tile i+1 into other buffer ----
            short4 sn;
            sn.x = f2bf((vA[0] - mean) * rstd); sn.y = f2bf((vA[1] - mean) * rstd);
            sn.z = f2bf((vA[2] - mean) * rstd); sn.w = f2bf((vA[3] - mean) * rstd);
            *reinterpret_cast<short4*>(&vt[cur ^ 1][ldsw]) = sn;

            asm volatile("s_waitcnt lgkmcnt(0)" ::: "memory");
            __builtin_amdgcn_s_barrier();
            vA = vB; uA = uB; uB = uC; sA = sB;
        }

        // ---- publish partials for batch g+1 ----
        if (doStats) {
            float r1 = aS, r2 = aQ;
            #pragma unroll
            for (int off = 32; off; off >>= 1) {
                r1 += __shfl_xor(r1, off);
                r2 += __shfl_xor(r2, off);
            }
            if (lane == 0) red2[wid] = make_float2(r1, r2);
            __syncthreads();
            if (wid == 0 && lane < 16) {
                float2 pr = red2[lane];
                float s1 = pr.x, s2 = pr.y;
                s1 += __shfl_xor(s1, 8);  s2 += __shfl_xor(s2, 8);
                s1 += __shfl_xor(s1, 4);  s2 += __shfl_xor(s2, 4);
                s1 += __shfl_xor(s1, 2);  s2 += __shfl_xor(s2, 2);
                s1 += __shfl_xor(s1, 1);  s2 += __shfl_xor(s2, 1);
                if (lane == 0) partials[((size_t)(g + 1) << 8) + b] = make_float2(s1, s2);
            }
        }
        __threadfence();
        grid.sync();
    }
}

// ================= fallback (proven round-12 path) =========================
__global__ __launch_bounds__(256) void stats_partial(const float* __restrict__ x,
                                                     float2* __restrict__ partials) {
    int bid = blockIdx.x;
    int batch = bid >> 8;
    int blk   = bid & 255;
    const float* base = x + ((size_t)batch << 24) + (1u << 23) + ((size_t)blk << 15);
    int tid = threadIdx.x;
    float s1 = 0.f, s2 = 0.f;
    #pragma unroll
    for (int i = 0; i < 32; ++i) {
        float4 v = *reinterpret_cast<const float4*>(base + (size_t)(i * 256 + tid) * 4);
        s1 += v.x + v.y + v.z + v.w;
        s2 += v.x * v.x + v.y * v.y + v.z * v.z + v.w * v.w;
    }
    #pragma unroll
    for (int off = 32; off; off >>= 1) {
        s1 += __shfl_down(s1, off);
        s2 += __shfl_down(s2, off);
    }
    __shared__ float2 red[4];
    if ((tid & 63) == 0) red[tid >> 6] = make_float2(s1, s2);
    __syncthreads();
    if (tid == 0) {
        float a1 = 0.f, a2 = 0.f;
        #pragma unroll
        for (int w = 0; w < 4; ++w) { a1 += red[w].x; a2 += red[w].y; }
        partials[bid] = make_float2(a1, a2);
    }
}

__global__ __launch_bounds__(1024, 4) void fused_gemm(const float* __restrict__ x,
                                                      const float* __restrict__ W,
                                                      const float* __restrict__ bias,
                                                      const float2* __restrict__ partials,
                                                      float* __restrict__ out) {
    __shared__ short vt[2][16 * LDR];
    __shared__ float2 red2[16];
    __shared__ float2 bst[8];
    const int tid  = threadIdx.x;
    const int wid  = tid >> 6;
    const int lane = tid & 63;
    const int l15  = lane & 15;
    const int l4   = lane >> 4;
    const int q    = l15 & 3;
    const int qg   = l15 >> 2;

    {
        const int bb   = wid >> 1;
        const int half = wid & 1;
        const int li   = ((half << 6) + lane) << 1;
        float2 p0 = partials[(bb << 8) + li];
        float2 p1 = partials[(bb << 8) + li + 1];
        float s1 = p0.x + p1.x, s2 = p0.y + p1.y;
        #pragma unroll
        for (int off = 32; off; off >>= 1) {
            s1 += __shfl_down(s1, off);
            s2 += __shfl_down(s2, off);
        }
        if (lane == 0) red2[wid] = make_float2(s1, s2);
        __syncthreads();
        if (tid < 8) {
            float a1 = red2[2 * tid].x + red2[2 * tid + 1].x;
            float a2 = red2[2 * tid].y + red2[2 * tid + 1].y;
            float mean = a1 / N_PER_BATCH;
            float var  = a2 / N_PER_BATCH - mean * mean;
            bst[tid] = make_float2(mean, rsqrtf(var + 1e-5f));
        }
    }

    short8_t bfrag[8];
    {
        const float* wbase = W + (size_t)(wid * 16 + l15) * 256 + (l4 << 3);
        #pragma unroll
        for (int kb = 0; kb < 8; ++kb) {
            float4 p0 = *reinterpret_cast<const float4*>(wbase + kb * 32);
            float4 p1 = *reinterpret_cast<const float4*>(wbase + kb * 32 + 4);
            short8_t s;
            s[0] = f2bf(p0.x); s[1] = f2bf(p0.y); s[2] = f2bf(p0.z); s[3] = f2bf(p0.w);
            s[4] = f2bf(p1.x); s[5] = f2bf(p1.y); s[6] = f2bf(p1.z); s[7] = f2bf(p1.w);
            bfrag[kb] = s;
        }
    }
    float4 bq = *reinterpret_cast<const float4*>(bias + wid * 16 + (qg << 2));
    bq.x += 1.f; bq.y += 1.f; bq.z += 1.f; bq.w += 1.f;

    const int   srow = tid >> 6;
    const int   scol = (tid & 63) << 2;
    const size_t goff = (size_t)srow * 256 + scol;
    const int   ldsw = srow * LDR + scol;
    const size_t eoff = (size_t)(l4 * 4 + q) * 256 + wid * 16 + (qg << 2);
    const int   aoff = l15 * LDR + (l4 << 3);
    const int b = blockIdx.x;
    #define TILE(s) (16383 - (b + ((s) << 8)))
    #define VADDR(T) (x + ((size_t)((T) >> 11) << 24) + (1u << 23) + ((size_t)((T) & 2047) << 12))
    #define UADDR(T) (x + ((size_t)((T) >> 11) << 24) + ((size_t)((T) & 2047) << 12))

    __syncthreads();

    {
        const int T0 = TILE(0);
        const float2 ms0 = bst[T0 >> 11];
        float4 v0 = *reinterpret_cast<const float4*>(VADDR(T0) + goff);
        short4 s;
        s.x = f2bf((v0.x - ms0.x) * ms0.y); s.y = f2bf((v0.y - ms0.x) * ms0.y);
        s.z = f2bf((v0.z - ms0.x) * ms0.y); s.w = f2bf((v0.w - ms0.x) * ms0.y);
        *reinterpret_cast<short4*>(&vt[0][ldsw]) = s;
    }
    float4 vA = *reinterpret_cast<const float4*>(VADDR(TILE(1)) + goff);
    f32x4 uA = ntload4(UADDR(TILE(0)) + eoff);
    f32x4 uB = ntload4(UADDR(TILE(1)) + eoff);
    asm volatile("s_waitcnt lgkmcnt(0)" ::: "memory");
    __builtin_amdgcn_s_barrier();

    for (int s = 0; s < 64; ++s) {
        const int cur = s & 1;
        const int sp1 = (s + 1 < 64) ? s + 1 : 63;
        const int sp2 = (s + 2 < 64) ? s + 2 : 63;
        const int Ts  = TILE(s);
        const int Ts1 = TILE(sp1);
        const int Ts2 = TILE(sp2);

        float4 vB = *reinterpret_cast<const float4*>(VADDR(Ts2) + goff);
        f32x4 uC = ntload4(UADDR(Ts2) + eoff);
        const float2 ms1 = bst[Ts1 >> 11];

        f32x4 acc = {0.f, 0.f, 0.f, 0.f};
        #pragma unroll
        for (int kb = 0; kb < 8; ++kb) {
            short8_t a = *reinterpret_cast<const short8_t*>(&vt[cur][aoff + kb * 32]);
            acc = __builtin_amdgcn_mfma_f32_16x16x32_bf16(a, bfrag[kb], acc, 0, 0, 0);
        }

        float a0 = acc[0], a1 = acc[1], a2 = acc[2], a3 = acc[3];
        float e0 = __shfl_xor(a1, 1), e1 = __shfl_xor(a0, 1);
        float e2 = __shfl_xor(a3, 1), e3 = __shfl_xor(a2, 1);
        const bool qb0 = (q & 1);
        float w0 = qb0 ? e0 : a0;
        float w1 = qb0 ? a1 : e1;
        float w2 = qb0 ? e2 : a2;
        float w3 = qb0 ? a3 : e3;
        float t0 = __shfl_xor(w2, 2), t1v = __shfl_xor(w3, 2);
        float t2v = __shfl_xor(w0, 2), t3 = __shfl_xor(w1, 2);
        const bool qb1 = (q & 2);
        float x0 = qb1 ? t0 : w0;
        float x1 = qb1 ? t1v : w1;
        float x2 = qb1 ? w2 : t2v;
        float x3 = qb1 ? w3 : t3;

        f32x4 o;
        o[0] = uA[0] * (x0 + bq.x);
        o[1] = uA[1] * (x1 + bq.y);
        o[2] = uA[2] * (x2 + bq.z);
        o[3] = uA[3] * (x3 + bq.w);
        ntstore4(out + ((size_t)Ts << 12) + eoff, o);

        short4 sn;
        sn.x = f2bf((vA.x - ms1.x) * ms1.y); sn.y = f2bf((vA.y - ms1.x) * ms1.y);
        sn.z = f2bf((vA.z - ms1.x) * ms1.y); sn.w = f2bf((vA.w - ms1.x) * ms1.y);
        *reinterpret_cast<short4*>(&vt[cur ^ 1][ldsw]) = sn;

        asm volatile("s_waitcnt lgkmcnt(0)" ::: "memory");
        __builtin_amdgcn_s_barrier();

        vA = vB; uA = uB; uB = uC;
    }
    #undef TILE
    #undef VADDR
    #undef UADDR
}

extern "C" void kernel_launch(void* const* d_in, const int* in_sizes, int n_in,
                              void* d_out, int out_size, void* d_ws, size_t ws_size,
                              hipStream_t stream) {
    const float* x    = (const float*)d_in[0];
    const float* W    = (const float*)d_in[1];
    const float* bias = (const float*)d_in[2];
    float* out = (float*)d_out;

    float2* partials = (float2*)d_ws;                       // 8*256 * 8 B

    void* args[] = {(void*)&x, (void*)&W, (void*)&bias, (void*)&partials, (void*)&out};
    hipError_t err = hipLaunchCooperativeKernel(reinterpret_cast<const void*>(mega),
                                                dim3(256), dim3(1024), args, 0, stream);
    if (err != hipSuccess) {
        // fallback: proven round-12 two-kernel path
        stats_partial<<<2048, 256, 0, stream>>>(x, partials);
        fused_gemm<<<256, 1024, 0, stream>>>(x, W, bias, partials, out);
    }
}

// Round 14
// 406.742 us; speedup vs baseline: 2.7381x; 2.7381x over previous
//
#include <hip/hip_runtime.h>
#include <hip/hip_bf16.h>

// ---- types ----
typedef __attribute__((ext_vector_type(8))) short short8_t;   // 8 x bf16 (4 VGPR)
typedef __attribute__((ext_vector_type(4))) float f32x4;      // MFMA acc / native float4

__device__ __forceinline__ short f2bf(float f) {
    union { float f; unsigned u; } v; v.f = f;
    unsigned r = (v.u + 0x7FFFu + ((v.u >> 16) & 1u)) >> 16;  // RNE
    return (short)r;
}

// non-temporal float4 helpers: u/out bypass cache so L3 keeps v.
__device__ __forceinline__ f32x4 ntload4(const float* p) {
    return __builtin_nontemporal_load(reinterpret_cast<const f32x4*>(p));
}
__device__ __forceinline__ void ntstore4(float* p, f32x4 v) {
    __builtin_nontemporal_store(v, reinterpret_cast<f32x4*>(p));
}

// Geometry: x[8][256][256][256] fp32. u = c in [0,128), v = c in [128,256).
// Per batch: 2048 16-row tiles; block b owns 8 tiles (rows b*128..b*128+127).
#define N_PER_BATCH 8388608.0f
#define LDR 264

// Custom lightweight grid barrier: agent-scope atomics only (NO grid.sync —
// cg's version does full L2 writeback/invalidate across 8 XCDs, ~110us each,
// measured round 13). Data handoff (partials, 2KB/phase) goes through
// agent-scope atomic stores/loads which are coherent at the MALL without
// flushing caches.
__device__ __forceinline__ void gridbar(unsigned* cnt, int idx, int tid) {
    __syncthreads();
    if (tid == 0) {
        __hip_atomic_fetch_add(&cnt[idx], 1u, __ATOMIC_ACQ_REL, __HIP_MEMORY_SCOPE_AGENT);
        while (__hip_atomic_load(&cnt[idx], __ATOMIC_ACQUIRE, __HIP_MEMORY_SCOPE_AGENT) < 256u) {
            __builtin_amdgcn_s_sleep(2);
        }
    }
    __syncthreads();
}

// ================== persistent phased kernel ==============================
// Phase A0: stats of batches 0,1 -> partials; bar0.
// Phase B_k (k=0..3), g=2k: finalize stats(g,g+1) from partials (agent atomic
// loads), GEMM+gate batches g,g+1 (v L3-hot from previous phase), interleaved
// streaming stats of batches g+2,g+3; publish; bar. v hits HBM once.
__global__ __launch_bounds__(1024, 4) void mega2(const float* __restrict__ x,
                                                 const float* __restrict__ W,
                                                 const float* __restrict__ bias,
                                                 float2* __restrict__ partials,
                                                 unsigned* __restrict__ cnt,
                                                 float* __restrict__ out) {
    __shared__ short vt[2][16 * LDR];   // 16896 B
    __shared__ float4 red4[16];
    __shared__ float2 bstL[2];
    const int tid  = threadIdx.x;
    const int wid  = tid >> 6;
    const int lane = tid & 63;
    const int l15  = lane & 15;
    const int l4   = lane >> 4;
    const int q    = l15 & 3;
    const int qg   = l15 >> 2;
    const int b    = blockIdx.x;

    // ---- B fragments: W[col][k], col = wid*16 + l15 ----
    short8_t bfrag[8];
    {
        const float* wbase = W + (size_t)(wid * 16 + l15) * 256 + (l4 << 3);
        #pragma unroll
        for (int kb = 0; kb < 8; ++kb) {
            float4 p0 = *reinterpret_cast<const float4*>(wbase + kb * 32);
            float4 p1 = *reinterpret_cast<const float4*>(wbase + kb * 32 + 4);
            short8_t s;
            s[0] = f2bf(p0.x); s[1] = f2bf(p0.y); s[2] = f2bf(p0.z); s[3] = f2bf(p0.w);
            s[4] = f2bf(p1.x); s[5] = f2bf(p1.y); s[6] = f2bf(p1.z); s[7] = f2bf(p1.w);
            bfrag[kb] = s;
        }
    }
    float4 bq = *reinterpret_cast<const float4*>(bias + wid * 16 + (qg << 2));
    bq.x += 1.f; bq.y += 1.f; bq.z += 1.f; bq.w += 1.f;

    const int   srow = tid >> 6;
    const int   scol = (tid & 63) << 2;
    const size_t goff = (size_t)srow * 256 + scol;
    const int   ldsw = srow * LDR + scol;
    const size_t eoff = (size_t)(l4 * 4 + q) * 256 + wid * 16 + (qg << 2);
    const int   aoff = l15 * LDR + (l4 << 3);

    // ---- publish helper (inlined twice) expects aS0,aQ0 (even batch) and
    //      aS1,aQ1 (odd batch); block-reduce; tid0 atomic-stores both ----
    #define PUBLISH2(gA, gB)                                                          \
    {                                                                                 \
        float r0 = aS0, r1 = aQ0, r2 = aS1, r3 = aQ1;                                 \
        _Pragma("unroll")                                                             \
        for (int off = 32; off; off >>= 1) {                                          \
            r0 += __shfl_xor(r0, off); r1 += __shfl_xor(r1, off);                     \
            r2 += __shfl_xor(r2, off); r3 += __shfl_xor(r3, off);                     \
        }                                                                             \
        if (lane == 0) { float4 t; t.x=r0; t.y=r1; t.z=r2; t.w=r3; red4[wid] = t; }   \
        __syncthreads();                                                              \
        if (wid == 0 && lane < 16) {                                                  \
            float4 t = red4[lane];                                                    \
            t.x += __shfl_xor(t.x, 8); t.y += __shfl_xor(t.y, 8);                     \
            t.z += __shfl_xor(t.z, 8); t.w += __shfl_xor(t.w, 8);                     \
            t.x += __shfl_xor(t.x, 4); t.y += __shfl_xor(t.y, 4);                     \
            t.z += __shfl_xor(t.z, 4); t.w += __shfl_xor(t.w, 4);                     \
            t.x += __shfl_xor(t.x, 2); t.y += __shfl_xor(t.y, 2);                     \
            t.z += __shfl_xor(t.z, 2); t.w += __shfl_xor(t.w, 2);                     \
            t.x += __shfl_xor(t.x, 1); t.y += __shfl_xor(t.y, 1);                     \
            t.z += __shfl_xor(t.z, 1); t.w += __shfl_xor(t.w, 1);                     \
            if (lane == 0) {                                                          \
                union { float2 f; unsigned long long u; } c0, c1;                     \
                c0.f = make_float2(t.x, t.y);  c1.f = make_float2(t.z, t.w);          \
                __hip_atomic_store((unsigned long long*)&partials[((size_t)(gA) << 8) + b], \
                                   c0.u, __ATOMIC_RELEASE, __HIP_MEMORY_SCOPE_AGENT); \
                __hip_atomic_store((unsigned long long*)&partials[((size_t)(gB) << 8) + b], \
                                   c1.u, __ATOMIC_RELEASE, __HIP_MEMORY_SCOPE_AGENT); \
            }                                                                         \
        }                                                                             \
    }

    // ---- Phase A0: stats of batches 0,1 (cached loads -> L3 warm) ----
    {
        float aS0 = 0.f, aQ0 = 0.f, aS1 = 0.f, aQ1 = 0.f;
        const float* s0b = x + (1u << 23) + ((size_t)b << 15) + (tid << 2);
        #pragma unroll
        for (int i = 0; i < 8; ++i) {
            f32x4 v = *reinterpret_cast<const f32x4*>(s0b + ((size_t)i << 12));
            aS0 += v[0] + v[1] + v[2] + v[3];
            aQ0 += v[0]*v[0] + v[1]*v[1] + v[2]*v[2] + v[3]*v[3];
        }
        const float* s1b = s0b + (1ull << 24);
        #pragma unroll
        for (int i = 0; i < 8; ++i) {
            f32x4 v = *reinterpret_cast<const f32x4*>(s1b + ((size_t)i << 12));
            aS1 += v[0] + v[1] + v[2] + v[3];
            aQ1 += v[0]*v[0] + v[1]*v[1] + v[2]*v[2] + v[3]*v[3];
        }
        PUBLISH2(0, 1)
    }
    gridbar(cnt, 0, tid);

    for (int k = 0; k < 4; ++k) {
        const int g = k << 1;
        const bool doStats = (k < 3);

        // ---- finalize stats(g + wid) for wid<2, via agent atomic loads ----
        if (wid < 2) {
            unsigned long long* p64 =
                (unsigned long long*)partials + (((size_t)(g + wid)) << 8);
            float s1 = 0.f, s2 = 0.f;
            #pragma unroll
            for (int j = 0; j < 4; ++j) {
                unsigned long long uv = __hip_atomic_load(&p64[(lane << 2) + j],
                                        __ATOMIC_ACQUIRE, __HIP_MEMORY_SCOPE_AGENT);
                union { unsigned long long u; float2 f; } c; c.u = uv;
                s1 += c.f.x; s2 += c.f.y;
            }
            #pragma unroll
            for (int off = 32; off; off >>= 1) {
                s1 += __shfl_xor(s1, off);
                s2 += __shfl_xor(s2, off);
            }
            if (lane == 0) {
                float mean = s1 / N_PER_BATCH;
                float var  = s2 / N_PER_BATCH - mean * mean;
                bstL[wid] = make_float2(mean, rsqrtf(var + 1e-5f));
            }
        }
        __syncthreads();
        const float mean0 = bstL[0].x, rstd0 = bstL[0].y;
        const float mean1 = bstL[1].x, rstd1 = bstL[1].y;

        // ---- prologue: stage tile 0 (batch g); prefetch v(1), u(0), u(1), s(0) ----
        {
            f32x4 v0 = *reinterpret_cast<const f32x4*>(
                x + ((size_t)g << 24) + (1u << 23) + ((size_t)b << 15) + goff);
            short4 s;
            s.x = f2bf((v0[0] - mean0) * rstd0); s.y = f2bf((v0[1] - mean0) * rstd0);
            s.z = f2bf((v0[2] - mean0) * rstd0); s.w = f2bf((v0[3] - mean0) * rstd0);
            *reinterpret_cast<short4*>(&vt[0][ldsw]) = s;
        }
        f32x4 vA = *reinterpret_cast<const f32x4*>(
            x + ((size_t)g << 24) + (1u << 23) + ((size_t)b << 15) + (1u << 12) + goff);
        f32x4 uA = ntload4(x + ((size_t)g << 24) + ((size_t)b << 15) + eoff);
        f32x4 uB = ntload4(x + ((size_t)g << 24) + ((size_t)b << 15) + (1u << 12) + eoff);
        f32x4 sA = {0.f, 0.f, 0.f, 0.f};
        if (doStats) sA = *reinterpret_cast<const f32x4*>(
            x + ((size_t)(g + 2) << 24) + (1u << 23) + ((size_t)b << 15) + (tid << 2));
        float aS0 = 0.f, aQ0 = 0.f, aS1 = 0.f, aQ1 = 0.f;
        asm volatile("s_waitcnt lgkmcnt(0)" ::: "memory");
        __builtin_amdgcn_s_barrier();

        for (int i = 0; i < 16; ++i) {
            const int cur = i & 1;
            const int in1 = (i + 1 < 16) ? i + 1 : 15;
            const int in2 = (i + 2 < 16) ? i + 2 : 15;

            // deep prefetches first (stay in flight across the barrier)
            const size_t base2 = ((size_t)(g + (in2 >> 3)) << 24) + ((size_t)b << 15)
                               + ((size_t)(in2 & 7) << 12);
            f32x4 vB = *reinterpret_cast<const f32x4*>(x + base2 + (1u << 23) + goff);
            f32x4 uC = ntload4(x + base2 + eoff);
            f32x4 sB = sA;
            if (doStats && i < 15)
                sB = *reinterpret_cast<const f32x4*>(
                    x + ((size_t)(g + 2 + (in1 >> 3)) << 24) + (1u << 23)
                      + ((size_t)b << 15) + ((size_t)(in1 & 7) << 12) + (tid << 2));

            // ---- MFMA over K=256 ----
            f32x4 acc = {0.f, 0.f, 0.f, 0.f};
            #pragma unroll
            for (int kb = 0; kb < 8; ++kb) {
                short8_t a = *reinterpret_cast<const short8_t*>(&vt[cur][aoff + kb * 32]);
                acc = __builtin_amdgcn_mfma_f32_16x16x32_bf16(a, bfrag[kb], acc, 0, 0, 0);
            }

            // ---- 4x4 transpose within lane quads ----
            float a0 = acc[0], a1 = acc[1], a2 = acc[2], a3 = acc[3];
            float e0 = __shfl_xor(a1, 1), e1 = __shfl_xor(a0, 1);
            float e2 = __shfl_xor(a3, 1), e3 = __shfl_xor(a2, 1);
            const bool qb0 = (q & 1);
            float w0 = qb0 ? e0 : a0;
            float w1 = qb0 ? a1 : e1;
            float w2 = qb0 ? e2 : a2;
            float w3 = qb0 ? a3 : e3;
            float t0 = __shfl_xor(w2, 2), t1 = __shfl_xor(w3, 2);
            float t2 = __shfl_xor(w0, 2), t3 = __shfl_xor(w1, 2);
            const bool qb1 = (q & 2);
            float x0 = qb1 ? t0 : w0;
            float x1 = qb1 ? t1 : w1;
            float x2 = qb1 ? w2 : t2;
            float x3 = qb1 ? w3 : t3;

            // ---- epilogue: out = u * (y + b + 1), non-temporal ----
            f32x4 o;
            o[0] = uA[0] * (x0 + bq.x);
            o[1] = uA[1] * (x1 + bq.y);
            o[2] = uA[2] * (x2 + bq.z);
            o[3] = uA[3] * (x3 + bq.w);
            ntstore4(out + (((size_t)((g + (i >> 3)) * 2048 + (b << 3) + (i & 7))) << 12)
                         + eoff, o);

            // ---- accumulate stats slab i of batch g+2+(i>>3) ----
            if (doStats) {
                if (i < 8) {
                    aS0 += sA[0] + sA[1] + sA[2] + sA[3];
                    aQ0 += sA[0]*sA[0] + sA[1]*sA[1] + sA[2]*sA[2] + sA[3]*sA[3];
                } else {
                    aS1 += sA[0] + sA[1] + sA[2] + sA[3];
                    aQ1 += sA[0]*sA[0] + sA[1]*sA[1] + sA[2]*sA[2] + sA[3]*sA[3];
                }
            }

            // ---- stage tile in1 with its batch's stats ----
            {
                const float ms = (in1 >= 8) ? mean1 : mean0;
                const float rs = (in1 >= 8) ? rstd1 : rstd0;
                short4 sn;
                sn.x = f2bf((vA[0] - ms) * rs); sn.y = f2bf((vA[1] - ms) * rs);
                sn.z = f2bf((vA[2] - ms) * rs); sn.w = f2bf((vA[3] - ms) * rs);
                *reinterpret_cast<short4*>(&vt[cur ^ 1][ldsw]) = sn;
            }

            asm volatile("s_waitcnt lgkmcnt(0)" ::: "memory");
            __builtin_amdgcn_s_barrier();
            vA = vB; uA = uB; uB = uC; sA = sB;
        }

        if (doStats) {
            PUBLISH2(g + 2, g + 3)
            gridbar(cnt, k + 1, tid);
        }
    }
    #undef PUBLISH2
}

// ================= fallback (proven round-12 path) =========================
__global__ __launch_bounds__(256) void stats_partial(const float* __restrict__ x,
                                                     float2* __restrict__ partials) {
    int bid = blockIdx.x;
    int batch = bid >> 8;
    int blk   = bid & 255;
    const float* base = x + ((size_t)batch << 24) + (1u << 23) + ((size_t)blk << 15);
    int tid = threadIdx.x;
    float s1 = 0.f, s2 = 0.f;
    #pragma unroll
    for (int i = 0; i < 32; ++i) {
        float4 v = *reinterpret_cast<const float4*>(base + (size_t)(i * 256 + tid) * 4);
        s1 += v.x + v.y + v.z + v.w;
        s2 += v.x * v.x + v.y * v.y + v.z * v.z + v.w * v.w;
    }
    #pragma unroll
    for (int off = 32; off; off >>= 1) {
        s1 += __shfl_down(s1, off);
        s2 += __shfl_down(s2, off);
    }
    __shared__ float2 red[4];
    if ((tid & 63) == 0) red[tid >> 6] = make_float2(s1, s2);
    __syncthreads();
    if (tid == 0) {
        float a1 = 0.f, a2 = 0.f;
        #pragma unroll
        for (int w = 0; w < 4; ++w) { a1 += red[w].x; a2 += red[w].y; }
        partials[bid] = make_float2(a1, a2);
    }
}

__global__ __launch_bounds__(1024, 4) void fused_gemm(const float* __restrict__ x,
                                                      const float* __restrict__ W,
                                                      const float* __restrict__ bias,
                                                      const float2* __restrict__ partials,
                                                      float* __restrict__ out) {
    __shared__ short vt[2][16 * LDR];
    __shared__ float2 red2[16];
    __shared__ float2 bst[8];
    const int tid  = threadIdx.x;
    const int wid  = tid >> 6;
    const int lane = tid & 63;
    const int l15  = lane & 15;
    const int l4   = lane >> 4;
    const int q    = l15 & 3;
    const int qg   = l15 >> 2;

    {
        const int bb   = wid >> 1;
        const int half = wid & 1;
        const int li   = ((half << 6) + lane) << 1;
        float2 p0 = partials[(bb << 8) + li];
        float2 p1 = partials[(bb << 8) + li + 1];
        float s1 = p0.x + p1.x, s2 = p0.y + p1.y;
        #pragma unroll
        for (int off = 32; off; off >>= 1) {
            s1 += __shfl_down(s1, off);
            s2 += __shfl_down(s2, off);
        }
        if (lane == 0) red2[wid] = make_float2(s1, s2);
        __syncthreads();
        if (tid < 8) {
            float a1 = red2[2 * tid].x + red2[2 * tid + 1].x;
            float a2 = red2[2 * tid].y + red2[2 * tid + 1].y;
            float mean = a1 / N_PER_BATCH;
            float var  = a2 / N_PER_BATCH - mean * mean;
            bst[tid] = make_float2(mean, rsqrtf(var + 1e-5f));
        }
    }

    short8_t bfrag[8];
    {
        const float* wbase = W + (size_t)(wid * 16 + l15) * 256 + (l4 << 3);
        #pragma unroll
        for (int kb = 0; kb < 8; ++kb) {
            float4 p0 = *reinterpret_cast<const float4*>(wbase + kb * 32);
            float4 p1 = *reinterpret_cast<const float4*>(wbase + kb * 32 + 4);
            short8_t s;
            s[0] = f2bf(p0.x); s[1] = f2bf(p0.y); s[2] = f2bf(p0.z); s[3] = f2bf(p0.w);
            s[4] = f2bf(p1.x); s[5] = f2bf(p1.y); s[6] = f2bf(p1.z); s[7] = f2bf(p1.w);
            bfrag[kb] = s;
        }
    }
    float4 bq = *reinterpret_cast<const float4*>(bias + wid * 16 + (qg << 2));
    bq.x += 1.f; bq.y += 1.f; bq.z += 1.f; bq.w += 1.f;

    const int   srow = tid >> 6;
    const int   scol = (tid & 63) << 2;
    const size_t goff = (size_t)srow * 256 + scol;
    const int   ldsw = srow * LDR + scol;
    const size_t eoff = (size_t)(l4 * 4 + q) * 256 + wid * 16 + (qg << 2);
    const int   aoff = l15 * LDR + (l4 << 3);
    const int b = blockIdx.x;
    #define TILE(s) (16383 - (b + ((s) << 8)))
    #define VADDR(T) (x + ((size_t)((T) >> 11) << 24) + (1u << 23) + ((size_t)((T) & 2047) << 12))
    #define UADDR(T) (x + ((size_t)((T) >> 11) << 24) + ((size_t)((T) & 2047) << 12))

    __syncthreads();

    {
        const int T0 = TILE(0);
        const float2 ms0 = bst[T0 >> 11];
        float4 v0 = *reinterpret_cast<const float4*>(VADDR(T0) + goff);
        short4 s;
        s.x = f2bf((v0.x - ms0.x) * ms0.y); s.y = f2bf((v0.y - ms0.x) * ms0.y);
        s.z = f2bf((v0.z - ms0.x) * ms0.y); s.w = f2bf((v0.w - ms0.x) * ms0.y);
        *reinterpret_cast<short4*>(&vt[0][ldsw]) = s;
    }
    float4 vA = *reinterpret_cast<const float4*>(VADDR(TILE(1)) + goff);
    f32x4 uA = ntload4(UADDR(TILE(0)) + eoff);
    f32x4 uB = ntload4(UADDR(TILE(1)) + eoff);
    asm volatile("s_waitcnt lgkmcnt(0)" ::: "memory");
    __builtin_amdgcn_s_barrier();

    for (int s = 0; s < 64; ++s) {
        const int cur = s & 1;
        const int sp1 = (s + 1 < 64) ? s + 1 : 63;
        const int sp2 = (s + 2 < 64) ? s + 2 : 63;
        const int Ts  = TILE(s);
        const int Ts1 = TILE(sp1);
        const int Ts2 = TILE(sp2);

        float4 vB = *reinterpret_cast<const float4*>(VADDR(Ts2) + goff);
        f32x4 uC = ntload4(UADDR(Ts2) + eoff);
        const float2 ms1 = bst[Ts1 >> 11];

        f32x4 acc = {0.f, 0.f, 0.f, 0.f};
        #pragma unroll
        for (int kb = 0; kb < 8; ++kb) {
            short8_t a = *reinterpret_cast<const short8_t*>(&vt[cur][aoff + kb * 32]);
            acc = __builtin_amdgcn_mfma_f32_16x16x32_bf16(a, bfrag[kb], acc, 0, 0, 0);
        }

        float a0 = acc[0], a1 = acc[1], a2 = acc[2], a3 = acc[3];
        float e0 = __shfl_xor(a1, 1), e1 = __shfl_xor(a0, 1);
        float e2 = __shfl_xor(a3, 1), e3 = __shfl_xor(a2, 1);
        const bool qb0 = (q & 1);
        float w0 = qb0 ? e0 : a0;
        float w1 = qb0 ? a1 : e1;
        float w2 = qb0 ? e2 : a2;
        float w3 = qb0 ? a3 : e3;
        float t0 = __shfl_xor(w2, 2), t1v = __shfl_xor(w3, 2);
        float t2v = __shfl_xor(w0, 2), t3 = __shfl_xor(w1, 2);
        const bool qb1 = (q & 2);
        float x0 = qb1 ? t0 : w0;
        float x1 = qb1 ? t1v : w1;
        float x2 = qb1 ? w2 : t2v;
        float x3 = qb1 ? w3 : t3;

        f32x4 o;
        o[0] = uA[0] * (x0 + bq.x);
        o[1] = uA[1] * (x1 + bq.y);
        o[2] = uA[2] * (x2 + bq.z);
        o[3] = uA[3] * (x3 + bq.w);
        ntstore4(out + ((size_t)Ts << 12) + eoff, o);

        short4 sn;
        sn.x = f2bf((vA.x - ms1.x) * ms1.y); sn.y = f2bf((vA.y - ms1.x) * ms1.y);
        sn.z = f2bf((vA.z - ms1.x) * ms1.y); sn.w = f2bf((vA.w - ms1.x) * ms1.y);
        *reinterpret_cast<short4*>(&vt[cur ^ 1][ldsw]) = sn;

        asm volatile("s_waitcnt lgkmcnt(0)" ::: "memory");
        __builtin_amdgcn_s_barrier();

        vA = vB; uA = uB; uB = uC;
    }
    #undef TILE
    #undef VADDR
    #undef UADDR
}

extern "C" void kernel_launch(void* const* d_in, const int* in_sizes, int n_in,
                              void* d_out, int out_size, void* d_ws, size_t ws_size,
                              hipStream_t stream) {
    const float* x    = (const float*)d_in[0];
    const float* W    = (const float*)d_in[1];
    const float* bias = (const float*)d_in[2];
    float* out = (float*)d_out;

    unsigned* cnt      = (unsigned*)d_ws;                     // 4 counters (256 B pad)
    float2*   partials = (float2*)((char*)d_ws + 256);        // 8*256 * 8 B

    // zero barrier counters (captured into the graph, runs every replay)
    hipMemsetAsync(d_ws, 0, 256, stream);

    void* args[] = {(void*)&x, (void*)&W, (void*)&bias, (void*)&partials,
                    (void*)&cnt, (void*)&out};
    hipError_t err = hipLaunchCooperativeKernel(reinterpret_cast<const void*>(mega2),
                                                dim3(256), dim3(1024), args, 0, stream);
    if (err != hipSuccess) {
        // fallback: proven round-12 two-kernel path
        float2* p2 = (float2*)d_ws;
        stats_partial<<<2048, 256, 0, stream>>>(x, p2);
        fused_gemm<<<256, 1024, 0, stream>>>(x, W, bias, p2, out);
    }
}

// Round 15
// 182.811 us; speedup vs baseline: 6.0920x; 2.2249x over previous
//
#include <hip/hip_runtime.h>
#include <hip/hip_bf16.h>

// ---- types ----
typedef __attribute__((ext_vector_type(8))) short short8_t;   // 8 x bf16 (4 VGPR)
typedef __attribute__((ext_vector_type(4))) float f32x4;      // MFMA acc / native float4

__device__ __forceinline__ short f2bf(float f) {
    union { float f; unsigned u; } v; v.f = f;
    unsigned r = (v.u + 0x7FFFu + ((v.u >> 16) & 1u)) >> 16;  // RNE
    return (short)r;
}

// non-temporal float4 helpers (native clang vector type). u/out bypass the
// Infinity Cache so v (resident in L3 from stats_partial) survives for re-read.
__device__ __forceinline__ f32x4 ntload4(const float* p) {
    return __builtin_nontemporal_load(reinterpret_cast<const f32x4*>(p));
}
__device__ __forceinline__ void ntstore4(float* p, f32x4 v) {
    __builtin_nontemporal_store(v, reinterpret_cast<f32x4*>(p));
}

// Geometry: x[8][256][256][256] fp32. u = c in [0,128), v = c in [128,256).
// M = 262144 rows of 256. 16384 16-row tiles; 2048 tiles per batch.
#define N_PER_BATCH 8388608.0f
#define LDR 264                  // padded LDS row (bf16): A-reads 2-way banks (free)

// ---------------- kernel 1: per-block partial sums over v ----------------
// Cached loads on purpose: this pass populates L3 with v (freshest = end).
__global__ __launch_bounds__(256) void stats_partial(const float* __restrict__ x,
                                                     float2* __restrict__ partials) {
    int bid = blockIdx.x;
    int batch = bid >> 8;
    int blk   = bid & 255;
    const float* base = x + ((size_t)batch << 24) + (1u << 23) + ((size_t)blk << 15);
    int tid = threadIdx.x;
    float s1 = 0.f, s2 = 0.f;
    #pragma unroll
    for (int i = 0; i < 32; ++i) {
        float4 v = *reinterpret_cast<const float4*>(base + (size_t)(i * 256 + tid) * 4);
        s1 += v.x + v.y + v.z + v.w;
        s2 += v.x * v.x + v.y * v.y + v.z * v.z + v.w * v.w;
    }
    #pragma unroll
    for (int off = 32; off; off >>= 1) {
        s1 += __shfl_down(s1, off);
        s2 += __shfl_down(s2, off);
    }
    __shared__ float2 red[4];
    if ((tid & 63) == 0) red[tid >> 6] = make_float2(s1, s2);
    __syncthreads();
    if (tid == 0) {
        float a1 = 0.f, a2 = 0.f;
        #pragma unroll
        for (int w = 0; w < 4; ++w) { a1 += red[w].x; a2 += red[w].y; }
        partials[bid] = make_float2(a1, a2);
    }
}

// ---------------- kernel 2: fused finalize + normalize + GEMM + gate ------
// Prologue: each block redundantly reduces the 2048 partials (16 KB, L2) to
// per-batch (mean, rstd) in LDS. Then: REVERSE GRID-STRIDED tile walk
// (block b does tiles 16383-(b+s*256)): at s=0 the GPU touches the freshest
// v lines in L3 and walks backward; all blocks cluster in one span per
// stream. u loads / out stores non-temporal; v cached. v prefetch 2 deep,
// u 2 deep; lgkmcnt-only barrier keeps global loads in flight.
__global__ __launch_bounds__(1024, 4) void fused_gemm(const float* __restrict__ x,
                                                      const float* __restrict__ W,
                                                      const float* __restrict__ bias,
                                                      const float2* __restrict__ partials,
                                                      float* __restrict__ out) {
    __shared__ short vt[2][16 * LDR];   // 16896 B
    __shared__ float2 red2[16];
    __shared__ float2 bst[8];           // per-batch (mean, rstd)
    const int tid  = threadIdx.x;
    const int wid  = tid >> 6;
    const int lane = tid & 63;
    const int l15  = lane & 15;
    const int l4   = lane >> 4;
    const int q    = l15 & 3;
    const int qg   = l15 >> 2;

    // ---- finalize stats in-block: wave pair (2w, 2w+1) reduces batch w>>1 ----
    {
        const int bb   = wid >> 1;               // batch this wave helps reduce
        const int half = wid & 1;
        const int li   = ((half << 6) + lane) << 1;   // 0..254 step 2
        float2 p0 = partials[(bb << 8) + li];
        float2 p1 = partials[(bb << 8) + li + 1];
        float s1 = p0.x + p1.x, s2 = p0.y + p1.y;
        #pragma unroll
        for (int off = 32; off; off >>= 1) {
            s1 += __shfl_down(s1, off);
            s2 += __shfl_down(s2, off);
        }
        if (lane == 0) red2[wid] = make_float2(s1, s2);
        __syncthreads();
        if (tid < 8) {
            float a1 = red2[2 * tid].x + red2[2 * tid + 1].x;
            float a2 = red2[2 * tid].y + red2[2 * tid + 1].y;
            float mean = a1 / N_PER_BATCH;
            float var  = a2 / N_PER_BATCH - mean * mean;
            bst[tid] = make_float2(mean, rsqrtf(var + 1e-5f));
        }
    }

    // ---- B fragments: W[col][k], col = wid*16 + l15, k = kb*32 + l4*8 + j ----
    short8_t bfrag[8];
    {
        const float* wbase = W + (size_t)(wid * 16 + l15) * 256 + (l4 << 3);
        #pragma unroll
        for (int kb = 0; kb < 8; ++kb) {
            float4 p0 = *reinterpret_cast<const float4*>(wbase + kb * 32);
            float4 p1 = *reinterpret_cast<const float4*>(wbase + kb * 32 + 4);
            short8_t s;
            s[0] = f2bf(p0.x); s[1] = f2bf(p0.y); s[2] = f2bf(p0.z); s[3] = f2bf(p0.w);
            s[4] = f2bf(p1.x); s[5] = f2bf(p1.y); s[6] = f2bf(p1.z); s[7] = f2bf(p1.w);
            bfrag[kb] = s;
        }
    }
    // bias (+1) for post-transpose cols: wid*16 + qg*4 + (0..3)
    float4 bq = *reinterpret_cast<const float4*>(bias + wid * 16 + (qg << 2));
    bq.x += 1.f; bq.y += 1.f; bq.z += 1.f; bq.w += 1.f;

    // staging role: 1024 float4 per tile / 1024 thr = 1 each
    const int   srow = tid >> 6;
    const int   scol = (tid & 63) << 2;
    const size_t goff = (size_t)srow * 256 + scol;   // within-tile v offset
    const int   ldsw = srow * LDR + scol;

    // per-wave epilogue offset: row = l4*4+q, cols = wid*16 + qg*4
    const size_t eoff = (size_t)(l4 * 4 + q) * 256 + wid * 16 + (qg << 2);

    // A-frag LDS base: row = l15, k-offset = l4*8
    const int aoff = l15 * LDR + (l4 << 3);

    const int b = blockIdx.x;
    #define TILE(s) (16383 - (b + ((s) << 8)))
    #define VADDR(T) (x + ((size_t)((T) >> 11) << 24) + (1u << 23) + ((size_t)((T) & 2047) << 12))
    #define UADDR(T) (x + ((size_t)((T) >> 11) << 24) + ((size_t)((T) & 2047) << 12))

    __syncthreads();   // bst ready

    // ---- prologue: stage tile(0); start v(1); u(0), u(1) ----
    {
        const int T0 = TILE(0);
        const float2 ms0 = bst[T0 >> 11];
        float4 v0 = *reinterpret_cast<const float4*>(VADDR(T0) + goff);
        short4 s;
        s.x = f2bf((v0.x - ms0.x) * ms0.y); s.y = f2bf((v0.y - ms0.x) * ms0.y);
        s.z = f2bf((v0.z - ms0.x) * ms0.y); s.w = f2bf((v0.w - ms0.x) * ms0.y);
        *reinterpret_cast<short4*>(&vt[0][ldsw]) = s;
    }
    float4 vA = *reinterpret_cast<const float4*>(VADDR(TILE(1)) + goff);   // v(1)
    f32x4 uA = ntload4(UADDR(TILE(0)) + eoff);                             // u(0)
    f32x4 uB = ntload4(UADDR(TILE(1)) + eoff);                             // u(1)
    asm volatile("s_waitcnt lgkmcnt(0)" ::: "memory");
    __builtin_amdgcn_s_barrier();

    for (int s = 0; s < 64; ++s) {
        const int cur = s & 1;
        const int sp1 = (s + 1 < 64) ? s + 1 : 63;
        const int sp2 = (s + 2 < 64) ? s + 2 : 63;
        const int Ts  = TILE(s);
        const int Ts1 = TILE(sp1);
        const int Ts2 = TILE(sp2);

        // deep prefetches first (stay in flight across the barrier)
        float4 vB = *reinterpret_cast<const float4*>(VADDR(Ts2) + goff);
        f32x4 uC = ntload4(UADDR(Ts2) + eoff);
        const float2 ms1 = bst[Ts1 >> 11];    // stats for the tile being staged

        // ---- MFMA over K=256 ----
        f32x4 acc = {0.f, 0.f, 0.f, 0.f};
        #pragma unroll
        for (int kb = 0; kb < 8; ++kb) {
            short8_t a = *reinterpret_cast<const short8_t*>(&vt[cur][aoff + kb * 32]);
            acc = __builtin_amdgcn_mfma_f32_16x16x32_bf16(a, bfrag[kb], acc, 0, 0, 0);
        }

        // ---- 4x4 transpose within lane quads: reg r <-> lane q ----
        float a0 = acc[0], a1 = acc[1], a2 = acc[2], a3 = acc[3];
        float s0 = __shfl_xor(a1, 1), s1v = __shfl_xor(a0, 1);
        float s2v = __shfl_xor(a3, 1), s3 = __shfl_xor(a2, 1);
        const bool qb0 = (q & 1);
        float w0 = qb0 ? s0 : a0;
        float w1 = qb0 ? a1 : s1v;
        float w2 = qb0 ? s2v : a2;
        float w3 = qb0 ? a3 : s3;
        float t0 = __shfl_xor(w2, 2), t1v = __shfl_xor(w3, 2);
        float t2v = __shfl_xor(w0, 2), t3 = __shfl_xor(w1, 2);
        const bool qb1 = (q & 2);
        float x0 = qb1 ? t0 : w0;
        float x1 = qb1 ? t1v : w1;
        float x2 = qb1 ? w2 : t2v;
        float x3 = qb1 ? w3 : t3;

        // ---- epilogue: out = u * (y + b + 1), non-temporal store ----
        f32x4 o;
        o[0] = uA[0] * (x0 + bq.x);
        o[1] = uA[1] * (x1 + bq.y);
        o[2] = uA[2] * (x2 + bq.z);
        o[3] = uA[3] * (x3 + bq.w);
        ntstore4(out + ((size_t)Ts << 12) + eoff, o);

        // ---- stage tile(s+1) (vA) into other buffer, with ITS batch stats ----
        short4 sn;
        sn.x = f2bf((vA.x - ms1.x) * ms1.y); sn.y = f2bf((vA.y - ms1.x) * ms1.y);
        sn.z = f2bf((vA.z - ms1.x) * ms1.y); sn.w = f2bf((vA.w - ms1.x) * ms1.y);
        *reinterpret_cast<short4*>(&vt[cur ^ 1][ldsw]) = sn;

        // raw barrier: drain LDS only, keep global loads in flight
        asm volatile("s_waitcnt lgkmcnt(0)" ::: "memory");
        __builtin_amdgcn_s_barrier();

        vA = vB; uA = uB; uB = uC;
    }
    #undef TILE
    #undef VADDR
    #undef UADDR
}

extern "C" void kernel_launch(void* const* d_in, const int* in_sizes, int n_in,
                              void* d_out, int out_size, void* d_ws, size_t ws_size,
                              hipStream_t stream) {
    const float* x    = (const float*)d_in[0];
    const float* W    = (const float*)d_in[1];
    const float* bias = (const float*)d_in[2];
    float* out = (float*)d_out;

    float2* partials = (float2*)d_ws;                       // 2048 * 8 B

    stats_partial<<<2048, 256, 0, stream>>>(x, partials);
    fused_gemm<<<256, 1024, 0, stream>>>(x, W, bias, partials, out);
}